// Round 1
// baseline (1582.728 us; speedup 1.0000x reference)
//
#include <hip/hip_runtime.h>
#include <math.h>

#define F 128
#define R 16
#define O 12

// ---------------- zero accumulator ----------------
__global__ void zero_kernel(float4* __restrict__ p, int n4) {
    int i = blockIdx.x * blockDim.x + threadIdx.x;
    if (i < n4) p[i] = make_float4(0.f, 0.f, 0.f, 0.f);
}

// ---------------- fused rbf-linear * gate -> scatter-add ----------------
// thread layout: 32 lanes cover the 128 features (4 per lane via float4),
// 8 edge-slots per 256-thread block, grid-stride over edges.
// W_rbf rows for this lane's 4 features live in registers (64 VGPRs).
__global__ __launch_bounds__(256) void scatter_gate(
    const float* __restrict__ m, const float* __restrict__ rbf,
    const int* __restrict__ idx1, const float* __restrict__ Wrbf,
    float* __restrict__ acc, int E)
{
    int t  = threadIdx.x;
    int fb = (t & 31) << 2;               // feature base: 0,4,...,124

    float4 Wr[4][4];
    #pragma unroll
    for (int ff = 0; ff < 4; ff++)
        #pragma unroll
        for (int q = 0; q < 4; q++)
            Wr[ff][q] = *(const float4*)(Wrbf + (fb + ff) * R + q * 4);

    int es = t >> 5;                      // edge slot 0..7
    int stride = gridDim.x * 8;
    for (int e = blockIdx.x * 8 + es; e < E; e += stride) {
        int node = idx1[e];
        const float4* rp = (const float4*)(rbf + (size_t)e * R);
        float4 r0 = rp[0], r1 = rp[1], r2 = rp[2], r3 = rp[3];
        float4 mv = *(const float4*)(m + (size_t)e * F + fb);
        float mvv[4] = {mv.x, mv.y, mv.z, mv.w};
        float* dst = acc + (size_t)node * F + fb;
        #pragma unroll
        for (int ff = 0; ff < 4; ff++) {
            float d =
                r0.x * Wr[ff][0].x + r0.y * Wr[ff][0].y + r0.z * Wr[ff][0].z + r0.w * Wr[ff][0].w +
                r1.x * Wr[ff][1].x + r1.y * Wr[ff][1].y + r1.z * Wr[ff][1].z + r1.w * Wr[ff][1].w +
                r2.x * Wr[ff][2].x + r2.y * Wr[ff][2].y + r2.z * Wr[ff][2].z + r2.w * Wr[ff][2].w +
                r3.x * Wr[ff][3].x + r3.y * Wr[ff][3].y + r3.z * Wr[ff][3].z + r3.w * Wr[ff][3].w;
            atomicAdd(dst + ff, d * mvv[ff]);
        }
    }
}

// ---------------- dense layer: out[n,g] = silu(sum_f in[n,f]*W[g,f] + b[g]) ----------------
// Block: 256 threads, 64 nodes. W (64KB) in LDS, XOR-swizzled column groups
// (2-way bank conflict only). A read straight from global (16-lane broadcast
// dedups to 1 transaction). Register tile: 4 nodes x 8 outputs per thread.
__global__ __launch_bounds__(256) void mlp_layer(
    const float* __restrict__ in, const float* __restrict__ W,
    const float* __restrict__ b, float* __restrict__ out, int N)
{
    __shared__ float Ws[F * F];           // 64 KB
    int t = threadIdx.x;
    int base = blockIdx.x * 64;

    for (int s = t; s < F * F / 4; s += 256) {
        int g = s >> 5, c = s & 31;
        float4 v = *(const float4*)(W + g * F + (c << 2));
        *(float4*)(Ws + g * F + ((c ^ (g & 31)) << 2)) = v;
    }
    __syncthreads();

    int j = t & 15, i = t >> 4;           // j: g-group, i: n-group
    float acc[4][8];
    #pragma unroll
    for (int k = 0; k < 4; k++)
        #pragma unroll
        for (int mm = 0; mm < 8; mm++) acc[k][mm] = 0.f;

    int  n0[4]; bool ok[4];
    #pragma unroll
    for (int k = 0; k < 4; k++) { n0[k] = base + i + 16 * k; ok[k] = n0[k] < N; }

    for (int c = 0; c < 32; c++) {
        int f = c << 2;
        float4 av[4];
        #pragma unroll
        for (int k = 0; k < 4; k++)
            av[k] = ok[k] ? *(const float4*)(in + (size_t)n0[k] * F + f)
                          : make_float4(0.f, 0.f, 0.f, 0.f);
        float4 wv[8];
        #pragma unroll
        for (int mm = 0; mm < 8; mm++) {
            int g = j + 16 * mm;
            wv[mm] = *(const float4*)(Ws + g * F + ((c ^ (g & 31)) << 2));
        }
        #pragma unroll
        for (int k = 0; k < 4; k++)
            #pragma unroll
            for (int mm = 0; mm < 8; mm++)
                acc[k][mm] += av[k].x * wv[mm].x + av[k].y * wv[mm].y +
                              av[k].z * wv[mm].z + av[k].w * wv[mm].w;
    }

    #pragma unroll
    for (int mm = 0; mm < 8; mm++) {
        int g = j + 16 * mm;
        float bias = b[g];
        #pragma unroll
        for (int k = 0; k < 4; k++) if (ok[k]) {
            float x = acc[k][mm] + bias;
            float y = x / (1.f + __expf(-x));   // silu
            out[(size_t)n0[k] * F + g] = y;
        }
    }
}

// ---------------- final projection: out[n,o] = sum_f act[n,f]*Wout[o,f] ----------------
// one wave per node; 6-step shuffle reduction per output.
__global__ __launch_bounds__(256) void proj_kernel(
    const float* __restrict__ act, const float* __restrict__ Wout,
    float* __restrict__ out, int N)
{
    __shared__ float Ws[O * F];
    int t = threadIdx.x;
    for (int s = t; s < O * F; s += 256) Ws[s] = Wout[s];
    __syncthreads();

    int w = t >> 6, lane = t & 63;
    int n = blockIdx.x * 4 + w;
    if (n >= N) return;

    float a0 = act[(size_t)n * F + lane];
    float a1 = act[(size_t)n * F + 64 + lane];
    #pragma unroll
    for (int o = 0; o < O; o++) {
        float p = a0 * Ws[o * F + lane] + a1 * Ws[o * F + 64 + lane];
        #pragma unroll
        for (int off = 32; off >= 1; off >>= 1) p += __shfl_xor(p, off, 64);
        if (lane == 0) out[n * O + o] = p;
    }
}

extern "C" void kernel_launch(void* const* d_in, const int* in_sizes, int n_in,
                              void* d_out, int out_size, void* d_ws, size_t ws_size,
                              hipStream_t stream)
{
    const float* m    = (const float*)d_in[0];
    const float* rbf  = (const float*)d_in[1];
    const int*   aei  = (const int*)d_in[2];
    const float* Wrbf = (const float*)d_in[3];
    const float* dW   = (const float*)d_in[4];
    const float* db   = (const float*)d_in[5];
    const float* Wout = (const float*)d_in[6];
    float* out = (float*)d_out;

    int E = in_sizes[0] / F;     // 640000
    int N = out_size / O;        // 20000

    float* A = (float*)d_ws;               // N*F accumulator / ping
    float* B = A + (size_t)N * F;          // pong

    int n4 = N * F / 4;
    zero_kernel<<<(n4 + 255) / 256, 256, 0, stream>>>((float4*)A, n4);

    // row 1 of atom_edge_index = receiving atoms
    scatter_gate<<<2048, 256, 0, stream>>>(m, rbf, aei + E, Wrbf, A, E);

    int mb = (N + 63) / 64;
    mlp_layer<<<mb, 256, 0, stream>>>(A, dW + 0 * F * F, db + 0 * F, B, N);
    mlp_layer<<<mb, 256, 0, stream>>>(B, dW + 1 * F * F, db + 1 * F, A, N);
    mlp_layer<<<mb, 256, 0, stream>>>(A, dW + 2 * F * F, db + 2 * F, B, N);

    proj_kernel<<<(N + 3) / 4, 256, 0, stream>>>(B, Wout, out, N);
}

// Round 2
// 818.565 us; speedup vs baseline: 1.9335x; 1.9335x over previous
//
#include <hip/hip_runtime.h>
#include <math.h>

#define F 128
#define R 16
#define O 12

// ---------------- small utility kernels ----------------
__global__ void zero_int_kernel(int* __restrict__ p, int n) {
    int i = blockIdx.x * blockDim.x + threadIdx.x;
    if (i < n) p[i] = 0;
}

// ---------------- CSR build: histogram ----------------
__global__ __launch_bounds__(256) void hist_kernel(
    const int* __restrict__ idx, int* __restrict__ cnt, int E)
{
    int i = blockIdx.x * blockDim.x + threadIdx.x;
    int stride = gridDim.x * blockDim.x;
    for (; i < E; i += stride) atomicAdd(&cnt[idx[i]], 1);
}

// ---------------- CSR build: exclusive scan (single block) ----------------
__global__ __launch_bounds__(1024) void scan_kernel(
    const int* __restrict__ cnt, int* __restrict__ off,
    int* __restrict__ cur, int N, int E)
{
    __shared__ int part[1024];
    int t = threadIdx.x;
    const int per = (N + 1023) / 1024;
    int s0 = t * per;
    int s = 0;
    for (int i = 0; i < per; i++) { int k = s0 + i; if (k < N) s += cnt[k]; }
    part[t] = s;
    __syncthreads();
    // Hillis-Steele inclusive scan over 1024 partials
    for (int d = 1; d < 1024; d <<= 1) {
        int v = (t >= d) ? part[t - d] : 0;
        __syncthreads();
        part[t] += v;
        __syncthreads();
    }
    int run = (t == 0) ? 0 : part[t - 1];
    for (int i = 0; i < per; i++) {
        int k = s0 + i;
        if (k < N) { off[k] = run; cur[k] = run; run += cnt[k]; }
    }
    if (t == 0) off[N] = E;
}

// ---------------- CSR build: fill edge lists ----------------
__global__ __launch_bounds__(256) void fill_kernel(
    const int* __restrict__ idx, int* __restrict__ cur,
    int* __restrict__ csr, int E)
{
    int i = blockIdx.x * blockDim.x + threadIdx.x;
    int stride = gridDim.x * blockDim.x;
    for (; i < E; i += stride) {
        int n = idx[i];
        int p = atomicAdd(&cur[n], 1);
        csr[p] = i;
    }
}

// ---------------- fused rbf-linear * gate -> GATHER (no atomics) ----------------
// One wave per node. Lane l owns features 2l, 2l+1. W_rbf rows in registers.
// m row load: lane l reads float2 at byte 8l of a 512B row -> one coalesced
// wave transaction. rbf row + csr entry are wave-uniform broadcasts.
__global__ __launch_bounds__(256) void gather_kernel(
    const float* __restrict__ m, const float* __restrict__ rbf,
    const int* __restrict__ csr, const int* __restrict__ off,
    const float* __restrict__ Wrbf, float* __restrict__ A, int N)
{
    int lane = threadIdx.x & 63;
    int w = threadIdx.x >> 6;
    int n = blockIdx.x * 4 + w;
    if (n >= N) return;

    int f0 = lane << 1;
    float4 W0[4], W1[4];
    #pragma unroll
    for (int q = 0; q < 4; q++) {
        W0[q] = *(const float4*)(Wrbf + (size_t)f0 * R + q * 4);
        W1[q] = *(const float4*)(Wrbf + (size_t)(f0 + 1) * R + q * 4);
    }

    float a0 = 0.f, a1 = 0.f;
    int jb = off[n], je = off[n + 1];

    int j = jb;
    for (; j + 1 < je; j += 2) {
        int e0 = csr[j], e1 = csr[j + 1];
        const float4* rpa = (const float4*)(rbf + (size_t)e0 * R);
        const float4* rpb = (const float4*)(rbf + (size_t)e1 * R);
        float4 p0 = rpa[0], p1 = rpa[1], p2 = rpa[2], p3 = rpa[3];
        float4 q0 = rpb[0], q1 = rpb[1], q2 = rpb[2], q3 = rpb[3];
        float2 ma = *(const float2*)(m + (size_t)e0 * F + f0);
        float2 mb = *(const float2*)(m + (size_t)e1 * F + f0);

        float d0a = p0.x*W0[0].x + p0.y*W0[0].y + p0.z*W0[0].z + p0.w*W0[0].w
                  + p1.x*W0[1].x + p1.y*W0[1].y + p1.z*W0[1].z + p1.w*W0[1].w
                  + p2.x*W0[2].x + p2.y*W0[2].y + p2.z*W0[2].z + p2.w*W0[2].w
                  + p3.x*W0[3].x + p3.y*W0[3].y + p3.z*W0[3].z + p3.w*W0[3].w;
        float d1a = p0.x*W1[0].x + p0.y*W1[0].y + p0.z*W1[0].z + p0.w*W1[0].w
                  + p1.x*W1[1].x + p1.y*W1[1].y + p1.z*W1[1].z + p1.w*W1[1].w
                  + p2.x*W1[2].x + p2.y*W1[2].y + p2.z*W1[2].z + p2.w*W1[2].w
                  + p3.x*W1[3].x + p3.y*W1[3].y + p3.z*W1[3].z + p3.w*W1[3].w;
        float d0b = q0.x*W0[0].x + q0.y*W0[0].y + q0.z*W0[0].z + q0.w*W0[0].w
                  + q1.x*W0[1].x + q1.y*W0[1].y + q1.z*W0[1].z + q1.w*W0[1].w
                  + q2.x*W0[2].x + q2.y*W0[2].y + q2.z*W0[2].z + q2.w*W0[2].w
                  + q3.x*W0[3].x + q3.y*W0[3].y + q3.z*W0[3].z + q3.w*W0[3].w;
        float d1b = q0.x*W1[0].x + q0.y*W1[0].y + q0.z*W1[0].z + q0.w*W1[0].w
                  + q1.x*W1[1].x + q1.y*W1[1].y + q1.z*W1[1].z + q1.w*W1[1].w
                  + q2.x*W1[2].x + q2.y*W1[2].y + q2.z*W1[2].z + q2.w*W1[2].w
                  + q3.x*W1[3].x + q3.y*W1[3].y + q3.z*W1[3].z + q3.w*W1[3].w;

        a0 += d0a * ma.x + d0b * mb.x;
        a1 += d1a * ma.y + d1b * mb.y;
    }
    if (j < je) {
        int e0 = csr[j];
        const float4* rpa = (const float4*)(rbf + (size_t)e0 * R);
        float4 p0 = rpa[0], p1 = rpa[1], p2 = rpa[2], p3 = rpa[3];
        float2 ma = *(const float2*)(m + (size_t)e0 * F + f0);
        float d0a = p0.x*W0[0].x + p0.y*W0[0].y + p0.z*W0[0].z + p0.w*W0[0].w
                  + p1.x*W0[1].x + p1.y*W0[1].y + p1.z*W0[1].z + p1.w*W0[1].w
                  + p2.x*W0[2].x + p2.y*W0[2].y + p2.z*W0[2].z + p2.w*W0[2].w
                  + p3.x*W0[3].x + p3.y*W0[3].y + p3.z*W0[3].z + p3.w*W0[3].w;
        float d1a = p0.x*W1[0].x + p0.y*W1[0].y + p0.z*W1[0].z + p0.w*W1[0].w
                  + p1.x*W1[1].x + p1.y*W1[1].y + p1.z*W1[1].z + p1.w*W1[1].w
                  + p2.x*W1[2].x + p2.y*W1[2].y + p2.z*W1[2].z + p2.w*W1[2].w
                  + p3.x*W1[3].x + p3.y*W1[3].y + p3.z*W1[3].z + p3.w*W1[3].w;
        a0 += d0a * ma.x;
        a1 += d1a * ma.y;
    }

    *(float2*)(A + (size_t)n * F + f0) = make_float2(a0, a1);
}

// ---------------- dense layer: out[n,g] = silu(sum_f in[n,f]*W[g,f] + b[g]) ----------------
__global__ __launch_bounds__(256) void mlp_layer(
    const float* __restrict__ in, const float* __restrict__ W,
    const float* __restrict__ b, float* __restrict__ out, int N)
{
    __shared__ float Ws[F * F];           // 64 KB
    int t = threadIdx.x;
    int base = blockIdx.x * 64;

    for (int s = t; s < F * F / 4; s += 256) {
        int g = s >> 5, c = s & 31;
        float4 v = *(const float4*)(W + g * F + (c << 2));
        *(float4*)(Ws + g * F + ((c ^ (g & 31)) << 2)) = v;
    }
    __syncthreads();

    int j = t & 15, i = t >> 4;           // j: g-group, i: n-group
    float acc[4][8];
    #pragma unroll
    for (int k = 0; k < 4; k++)
        #pragma unroll
        for (int mm = 0; mm < 8; mm++) acc[k][mm] = 0.f;

    int  n0[4]; bool ok[4];
    #pragma unroll
    for (int k = 0; k < 4; k++) { n0[k] = base + i + 16 * k; ok[k] = n0[k] < N; }

    for (int c = 0; c < 32; c++) {
        int f = c << 2;
        float4 av[4];
        #pragma unroll
        for (int k = 0; k < 4; k++)
            av[k] = ok[k] ? *(const float4*)(in + (size_t)n0[k] * F + f)
                          : make_float4(0.f, 0.f, 0.f, 0.f);
        float4 wv[8];
        #pragma unroll
        for (int mm = 0; mm < 8; mm++) {
            int g = j + 16 * mm;
            wv[mm] = *(const float4*)(Ws + g * F + ((c ^ (g & 31)) << 2));
        }
        #pragma unroll
        for (int k = 0; k < 4; k++)
            #pragma unroll
            for (int mm = 0; mm < 8; mm++)
                acc[k][mm] += av[k].x * wv[mm].x + av[k].y * wv[mm].y +
                              av[k].z * wv[mm].z + av[k].w * wv[mm].w;
    }

    #pragma unroll
    for (int mm = 0; mm < 8; mm++) {
        int g = j + 16 * mm;
        float bias = b[g];
        #pragma unroll
        for (int k = 0; k < 4; k++) if (ok[k]) {
            float x = acc[k][mm] + bias;
            float y = x / (1.f + __expf(-x));   // silu
            out[(size_t)n0[k] * F + g] = y;
        }
    }
}

// ---------------- final projection: out[n,o] = sum_f act[n,f]*Wout[o,f] ----------------
__global__ __launch_bounds__(256) void proj_kernel(
    const float* __restrict__ act, const float* __restrict__ Wout,
    float* __restrict__ out, int N)
{
    __shared__ float Ws[O * F];
    int t = threadIdx.x;
    for (int s = t; s < O * F; s += 256) Ws[s] = Wout[s];
    __syncthreads();

    int w = t >> 6, lane = t & 63;
    int n = blockIdx.x * 4 + w;
    if (n >= N) return;

    float a0 = act[(size_t)n * F + lane];
    float a1 = act[(size_t)n * F + 64 + lane];
    #pragma unroll
    for (int o = 0; o < O; o++) {
        float p = a0 * Ws[o * F + lane] + a1 * Ws[o * F + 64 + lane];
        #pragma unroll
        for (int off = 32; off >= 1; off >>= 1) p += __shfl_xor(p, off, 64);
        if (lane == 0) out[n * O + o] = p;
    }
}

extern "C" void kernel_launch(void* const* d_in, const int* in_sizes, int n_in,
                              void* d_out, int out_size, void* d_ws, size_t ws_size,
                              hipStream_t stream)
{
    const float* m    = (const float*)d_in[0];
    const float* rbf  = (const float*)d_in[1];
    const int*   aei  = (const int*)d_in[2];
    const float* Wrbf = (const float*)d_in[3];
    const float* dW   = (const float*)d_in[4];
    const float* db   = (const float*)d_in[5];
    const float* Wout = (const float*)d_in[6];
    float* out = (float*)d_out;

    int E = in_sizes[0] / F;     // 640000
    int N = out_size / O;        // 20000

    // ws layout: A [N*F floats] | B [N*F floats].
    // CSR scratch aliases B (used before any MLP writes B): csr[E], cnt[N],
    // cur[N], off[N+1] -- total ~2.8 MB < 10.24 MB.
    float* A = (float*)d_ws;
    float* B = A + (size_t)N * F;
    int* csr = (int*)B;
    int* cnt = csr + E;
    int* cur = cnt + N;
    int* off = cur + N;

    const int* idx1 = aei + E;   // row 1 = receiving atoms

    zero_int_kernel<<<(N + 255) / 256, 256, 0, stream>>>(cnt, N);
    hist_kernel<<<1024, 256, 0, stream>>>(idx1, cnt, E);
    scan_kernel<<<1, 1024, 0, stream>>>(cnt, off, cur, N, E);
    fill_kernel<<<1024, 256, 0, stream>>>(idx1, cur, csr, E);
    gather_kernel<<<(N + 3) / 4, 256, 0, stream>>>(m, rbf, csr, off, Wrbf, A, N);

    int mb = (N + 63) / 64;
    mlp_layer<<<mb, 256, 0, stream>>>(A, dW + 0 * F * F, db + 0 * F, B, N);
    mlp_layer<<<mb, 256, 0, stream>>>(B, dW + 1 * F * F, db + 1 * F, A, N);
    mlp_layer<<<mb, 256, 0, stream>>>(A, dW + 2 * F * F, db + 2 * F, B, N);

    proj_kernel<<<(N + 3) / 4, 256, 0, stream>>>(B, Wout, out, N);
}